// Round 4
// baseline (1912.869 us; speedup 1.0000x reference)
//
#include <hip/hip_runtime.h>

// VQ-VAE vector quantizer, MI355X.
// Replicates the reference's fp32 arithmetic exactly:
//   dist = fl32( fl32(|z|^2 + |e_k|^2) - fl32(2 * dot) ), argmin ties -> lowest k.
// |z|^2 ~ 512 dominates: |e|^2 vanishes below half-ulp, dot is quantized to
// ulp(512)=6.1e-5 -- ties resolved by lowest index, matching np/jax fp32.
// z: [2,512,8,32,32] fp32 ; emb: [8192,512] fp32
// out: z_q_ste (8388608 f32) | vq_loss (1 f32) | indices (16384 f32)

constexpr int KCB = 8192;          // num embeddings
constexpr int CD  = 512;           // embedding dim
constexpr int SD  = 8192;          // 8*32*32
constexpr int NB  = 2;             // batch
constexpr int NR  = NB * SD;       // 16384 flattened vectors
constexpr long ZQ_ELEMS = (long)NB * CD * SD;   // 8388608

// ws layout (non-overlapping):
//   0       : double mse accumulator (8B)
//   4096    : u64 keys[16384]        (131072B) -> ends 135168
//   139264  : float znorm[16384]     (65536B)  -> ends 204800
//   212992  : float enorm[8192]      (32768B)  -> ends 245760
//   262144  : float emb_t[512*8192]  (16MB)    -> ends 17039360
constexpr size_t WS_KEYS  = 4096;
constexpr size_t WS_ZNORM = 139264;
constexpr size_t WS_ENORM = 212992;
constexpr size_t WS_EMBT  = 262144;

__device__ __forceinline__ unsigned int fkey(float f) {
  unsigned int b = __float_as_uint(f);
  return (b & 0x80000000u) ? ~b : (b | 0x80000000u);   // monotone float->uint
}

// ---- znorm[n] = fp32(sum_c z[n][c]^2), fp64 accumulate ----
// z layout [b][c][s]; row n=(b,s). 256 consecutive s per block: coalesced.
__global__ __launch_bounds__(256) void k_znorm(const float* __restrict__ z,
                                               float* __restrict__ znorm) {
  int n0 = blockIdx.x * 256;
  int b = n0 / SD, s0 = n0 % SD;
  const float* zp = z + (size_t)b * CD * SD + s0 + threadIdx.x;
  double a = 0.0;
  #pragma unroll 8
  for (int c = 0; c < CD; ++c) {
    double v = (double)zp[(size_t)c * SD];
    a = fma(v, v, a);
  }
  znorm[n0 + threadIdx.x] = (float)a;
}

// ---- enorm[k] = sum_c emb[k][c]^2 ; one wave per row ----
__global__ __launch_bounds__(256) void k_enorm(const float* __restrict__ emb,
                                               float* __restrict__ enorm) {
  int row  = blockIdx.x * 4 + (threadIdx.x >> 6);
  int lane = threadIdx.x & 63;
  const float4* p = (const float4*)(emb + (size_t)row * CD);
  float4 a = p[lane * 2], b = p[lane * 2 + 1];
  float s = a.x*a.x + a.y*a.y + a.z*a.z + a.w*a.w
          + b.x*b.x + b.y*b.y + b.z*b.z + b.w*b.w;
  #pragma unroll
  for (int off = 32; off; off >>= 1) s += __shfl_down(s, off);
  if (lane == 0) enorm[row] = s;
}

// ---- emb_t[c][k] = emb[k][c] ; 64x64 LDS tiles ----
__global__ __launch_bounds__(256) void k_transpose(const float* __restrict__ emb,
                                                   float* __restrict__ embt) {
  __shared__ float t[64][65];
  int bk = blockIdx.x & 127, bc = blockIdx.x >> 7;
  int k0 = bk * 64, c0 = bc * 64;
  int t4 = threadIdx.x & 15, tq = threadIdx.x >> 4;
  #pragma unroll
  for (int p = 0; p < 4; ++p) {
    int kk = p * 16 + tq;
    float4 v = *(const float4*)(emb + (size_t)(k0 + kk) * CD + c0 + 4 * t4);
    t[kk][4*t4+0] = v.x; t[kk][4*t4+1] = v.y; t[kk][4*t4+2] = v.z; t[kk][4*t4+3] = v.w;
  }
  __syncthreads();
  #pragma unroll
  for (int p = 0; p < 4; ++p) {
    int cc = p * 16 + tq;
    float4 v;
    v.x = t[4*t4+0][cc]; v.y = t[4*t4+1][cc]; v.z = t[4*t4+2][cc]; v.w = t[4*t4+3][cc];
    *(float4*)(embt + (size_t)(c0 + cc) * KCB + k0 + 4 * t4) = v;
  }
}

// ---- distance GEMM + fused argmin with reference-fp32 quantization ----
// 512 blocks x 256 thr. Block = 64 rows x one k-half (4096 cols), tiles of 128.
__global__ __launch_bounds__(256) void k_dist(const float* __restrict__ z,
                                              const float* __restrict__ embt,
                                              const float* __restrict__ enorm,
                                              const float* __restrict__ znorm,
                                              unsigned long long* __restrict__ keys) {
  __shared__ __align__(16) float zt[64][68];  // [ci][row] (reused as u64 red[])
  __shared__ float et[64][132];               // [ci][kcol]

  int tid    = threadIdx.x;
  int khalf  = blockIdx.x & 1;
  int rowblk = blockIdx.x >> 1;
  int n0 = rowblk * 64;
  int b  = n0 / SD, s0 = n0 % SD;
  const float* zb = z + (size_t)b * CD * SD;
  int kbase = khalf * 4096;

  int tr = tid >> 4, tc = tid & 15;
  int r0 = tr * 4, c0 = tc * 8;

  float A[4];
  #pragma unroll
  for (int r = 0; r < 4; ++r) A[r] = znorm[n0 + r0 + r];

  unsigned long long bkey[4];
  #pragma unroll
  for (int r = 0; r < 4; ++r) bkey[r] = ~0ull;

  int sci = tid >> 2;        // staging row 0..63
  int sl  = tid & 3;

  for (int kt = 0; kt < 32; ++kt) {
    int k0 = kbase + kt * 128;
    float acc[4][8];
    #pragma unroll
    for (int r = 0; r < 4; ++r)
      #pragma unroll
      for (int u = 0; u < 8; ++u) acc[r][u] = 0.f;

    for (int cc = 0; cc < 8; ++cc) {
      int cb = cc * 64;
      __syncthreads();
      {
        const float* src = zb + (size_t)(cb + sci) * SD + s0;
        #pragma unroll
        for (int p = 0; p < 4; ++p) {
          int r = sl * 4 + p * 16;
          *(float4*)&zt[sci][r] = *(const float4*)(src + r);
        }
        const float* esrc = embt + (size_t)(cb + sci) * KCB + k0;
        #pragma unroll
        for (int p = 0; p < 8; ++p) {
          int kk = sl * 4 + p * 16;
          *(float4*)&et[sci][kk] = *(const float4*)(esrc + kk);
        }
      }
      __syncthreads();
      #pragma unroll 8
      for (int ci = 0; ci < 64; ++ci) {
        float4 a4 = *(const float4*)&zt[ci][r0];
        float4 b0 = *(const float4*)&et[ci][c0];
        float4 b1 = *(const float4*)&et[ci][c0 + 4];
        float av[4] = {a4.x, a4.y, a4.z, a4.w};
        float bv[8] = {b0.x, b0.y, b0.z, b0.w, b1.x, b1.y, b1.z, b1.w};
        #pragma unroll
        for (int r = 0; r < 4; ++r)
          #pragma unroll
          for (int u = 0; u < 8; ++u)
            acc[r][u] = fmaf(av[r], bv[u], acc[r][u]);
      }
    }
    // Reference-replicating epilogue:
    //   d = fl32( fl32(A + enorm[k]) - 2f*dot )   (2f*dot exact; one rounding)
    // Key min == (min d, then min k): exactly np.argmin first-occurrence.
    #pragma unroll
    for (int u = 0; u < 8; ++u) {
      int k = k0 + c0 + u;
      float en = enorm[k];
      #pragma unroll
      for (int r = 0; r < 4; ++r) {
        float ab = A[r] + en;               // |e|^2 vanishes below half-ulp(512)
        float d  = ab - 2.0f * acc[r][u];   // quantized to ulp(~512) grid
        unsigned long long key =
            ((unsigned long long)fkey(d) << 32) | (unsigned int)k;
        if (key < bkey[r]) bkey[r] = key;
      }
    }
  }
  // block-level key-min per row (16 threads per row)
  __syncthreads();
  unsigned long long* red = (unsigned long long*)&zt[0][0];  // 64*16 u64 = 8KB
  #pragma unroll
  for (int r = 0; r < 4; ++r) red[(r0 + r) * 16 + tc] = bkey[r];
  __syncthreads();
  if (tid < 64) {
    unsigned long long m = ~0ull;
    #pragma unroll 4
    for (int i = 0; i < 16; ++i) {
      unsigned long long v = red[tid * 16 + i];
      if (v < m) m = v;
    }
    atomicMin(&keys[n0 + tid], m);   // combine the two khalf blocks
  }
}

// ---- gather + STE + mse partial ; 16 rows per block ----
__global__ __launch_bounds__(256) void k_gather(const float* __restrict__ z,
                                                const float* __restrict__ emb,
                                                const unsigned long long* __restrict__ keys,
                                                float* __restrict__ out,
                                                double* __restrict__ acc) {
  __shared__ float q[16][516];
  __shared__ int   idxs[16];
  __shared__ float wpart[4];
  int tid = threadIdx.x;
  int n0 = blockIdx.x * 16;
  int b = n0 / SD, s0 = n0 % SD;
  if (tid < 16) {
    int idx = (int)(keys[n0 + tid] & 0xFFFFFFFFull) & (KCB - 1);  // defensive
    idxs[tid] = idx;
    out[ZQ_ELEMS + 1 + n0 + tid] = (float)idx;   // indices output (as f32)
  }
  __syncthreads();
  int row = tid >> 4, c4 = (tid & 15) * 4;
  const float* esrc = emb + (size_t)idxs[row] * CD;
  #pragma unroll
  for (int p = 0; p < 8; ++p) {
    int c = c4 + p * 64;
    *(float4*)&q[row][c] = *(const float4*)(esrc + c);
  }
  __syncthreads();
  int si = tid & 15, cq = tid >> 4;
  float sum = 0.f;
  const float* zrd = z   + (size_t)b * CD * SD + s0 + si;
  float*       owr = out + (size_t)b * CD * SD + s0 + si;
  #pragma unroll
  for (int j = 0; j < 32; ++j) {
    int c = cq + 16 * j;
    float zv = zrd[(size_t)c * SD];
    float qv = q[si][c];
    float d = qv - zv;
    sum += d * d;
    owr[(size_t)c * SD] = zv + (qv - zv);   // straight-through value
  }
  #pragma unroll
  for (int off = 32; off; off >>= 1) sum += __shfl_down(sum, off);
  if ((tid & 63) == 0) wpart[tid >> 6] = sum;
  __syncthreads();
  if (tid == 0) {
    double t = (double)wpart[0] + (double)wpart[1] + (double)wpart[2] + (double)wpart[3];
    atomicAdd(acc, t);
  }
}

__global__ void k_loss(const double* __restrict__ acc, float* __restrict__ out) {
  out[ZQ_ELEMS] = (float)(1.25 * (*acc) / (double)ZQ_ELEMS);
}

extern "C" void kernel_launch(void* const* d_in, const int* in_sizes, int n_in,
                              void* d_out, int out_size, void* d_ws, size_t ws_size,
                              hipStream_t stream) {
  const float* z   = (const float*)d_in[0];
  const float* emb = (const float*)d_in[1];
  float* out = (float*)d_out;
  double*             acc   = (double*)d_ws;
  unsigned long long* keys  = (unsigned long long*)((char*)d_ws + WS_KEYS);
  float*              znorm = (float*)((char*)d_ws + WS_ZNORM);
  float*              enorm = (float*)((char*)d_ws + WS_ENORM);
  float*              embt  = (float*)((char*)d_ws + WS_EMBT);
  (void)in_sizes; (void)n_in; (void)out_size; (void)ws_size;

  hipMemsetAsync(d_ws, 0, 64, stream);                                  // mse acc
  hipMemsetAsync((char*)d_ws + WS_KEYS, 0xFF, (size_t)NR * 8, stream);  // keys

  k_znorm    <<<NR / 256, 256, 0, stream>>>(z, znorm);
  k_enorm    <<<KCB / 4, 256, 0, stream>>>(emb, enorm);
  k_transpose<<<(KCB / 64) * (CD / 64), 256, 0, stream>>>(emb, embt);
  k_dist     <<<512, 256, 0, stream>>>(z, embt, enorm, znorm, keys);
  k_gather   <<<NR / 16, 256, 0, stream>>>(z, emb, keys, out, acc);
  k_loss     <<<1, 1, 0, stream>>>(acc, out);
}